// Round 1
// baseline (82.248 us; speedup 1.0000x reference)
//
#include <hip/hip_runtime.h>

#define NN 4096
#define TTOT 8192

constexpr int TN = 64;       // n-rows per block
constexpr int TB = 64;       // t-cols per block
constexpr int S  = 16;       // t per thread
constexpr int HALO = 4;      // dependency cone of 4 kernel-2 layers
constexpr int PITCH = TN + 4; // 68 floats -> 272B rows, 16B aligned

__device__ inline float fast_exp2(float x) {
#if __has_builtin(__builtin_amdgcn_exp2f)
    return __builtin_amdgcn_exp2f(x);
#else
    return exp2f(x);
#endif
}
__device__ inline float fast_rcp(float x) {
#if __has_builtin(__builtin_amdgcn_rcpf)
    return __builtin_amdgcn_rcpf(x);
#else
    return 1.0f / x;
#endif
}

__global__ __launch_bounds__(256) void gdcn_kernel(
    const float* __restrict__ x,
    const float* __restrict__ start_w,
    const float* __restrict__ start_b,
    const float* __restrict__ filter_w,
    const float* __restrict__ filter_b,
    const float* __restrict__ gate_w,
    const float* __restrict__ gate_b,
    float* __restrict__ out)
{
    __shared__ float tile[TB][PITCH];

    const int tid = threadIdx.x;
    const int nblk = NN / TN;            // 64
    const int bn = blockIdx.x % nblk;
    const int bt = blockIdx.x / nblk;
    const int n0 = bn * TN;
    const int t0 = bt * TB;

    const int nl = tid & 63;             // lane -> n row (coalesced-ish reads, 16B/lane)
    const int ts = tid >> 6;             // wave id -> t segment (wave-uniform edge branch)
    const int tbase = t0 + ts * S;

    const float* xr = x + (size_t)(n0 + nl) * TTOT + tbase;

    float v[S + HALO];
    const bool edge = (tbase + S + HALO > TTOT);   // only last segment of last t-tile
    if (!edge) {
        #pragma unroll
        for (int q = 0; q < 5; ++q) {
            float4 f4 = *reinterpret_cast<const float4*>(xr + 4 * q);
            v[4*q+0] = f4.x; v[4*q+1] = f4.y; v[4*q+2] = f4.z; v[4*q+3] = f4.w;
        }
    } else {
        #pragma unroll
        for (int s = 0; s < S + HALO; ++s)
            v[s] = (tbase + s < TTOT) ? xr[s] : 0.0f;
    }

    const float LOG2E = 1.4426950408889634f;

    // start 1x1 conv
    {
        const float sw = start_w[0], sb = start_b[0];
        #pragma unroll
        for (int s = 0; s < S + HALO; ++s) v[s] = v[s] * sw + sb;
    }
    if (edge) {
        #pragma unroll
        for (int s = 0; s < S + HALO; ++s)
            if (tbase + s >= TTOT) v[s] = 0.0f;   // per-layer zero pad semantics
    }

    // 4 gated layers. tanh(p) = 1 - 2/(1+2^(2*log2e*p)); sigmoid(p) = 1/(1+2^(-log2e*p))
    #pragma unroll
    for (int i = 0; i < 4; ++i) {
        const float ff0 = filter_w[2*i]   * (2.0f * LOG2E);
        const float ff1 = filter_w[2*i+1] * (2.0f * LOG2E);
        const float ffb = filter_b[i]     * (2.0f * LOG2E);
        const float gg0 = -gate_w[2*i]    * LOG2E;
        const float gg1 = -gate_w[2*i+1]  * LOG2E;
        const float ggb = -gate_b[i]      * LOG2E;
        #pragma unroll
        for (int s = 0; s < S + HALO - 1 - i; ++s) {
            const float a = v[s], b = v[s + 1];
            const float ef = fast_exp2(ff0 * a + ff1 * b + ffb);
            const float f  = 1.0f - 2.0f * fast_rcp(1.0f + ef);
            const float eg = fast_exp2(gg0 * a + gg1 * b + ggb);
            const float g  = fast_rcp(1.0f + eg);
            v[s] = f * g;
        }
        if (edge) {
            #pragma unroll
            for (int s = 0; s < S + HALO - 1 - i; ++s)
                if (tbase + s >= TTOT) v[s] = 0.0f;
        }
    }

    // stage to LDS (stride-1 across lanes: conflict-free)
    #pragma unroll
    for (int s = 0; s < S; ++s)
        tile[ts * S + s][nl] = v[s];
    __syncthreads();

    // transposed, coalesced float4 writes: out[(t)*NN + n]
    const int tl = tid >> 4;             // 0..15
    const int nq = (tid & 15) * 4;
    #pragma unroll
    for (int k = 0; k < 4; ++k) {
        const int trow = tl + k * 16;
        float4 w4 = *reinterpret_cast<const float4*>(&tile[trow][nq]);
        *reinterpret_cast<float4*>(&out[(size_t)(t0 + trow) * NN + n0 + nq]) = w4;
    }
}

extern "C" void kernel_launch(void* const* d_in, const int* in_sizes, int n_in,
                              void* d_out, int out_size, void* d_ws, size_t ws_size,
                              hipStream_t stream) {
    const float* x  = (const float*)d_in[0];
    const float* sw = (const float*)d_in[1];
    const float* sb = (const float*)d_in[2];
    const float* fw = (const float*)d_in[3];
    const float* fb = (const float*)d_in[4];
    const float* gw = (const float*)d_in[5];
    const float* gb = (const float*)d_in[6];
    float* out = (float*)d_out;

    dim3 grid((NN / TN) * (TTOT / TB));
    gdcn_kernel<<<grid, 256, 0, stream>>>(x, sw, sb, fw, fb, gw, gb, out);
}

// Round 2
// 64.266 us; speedup vs baseline: 1.2798x; 1.2798x over previous
//
#include <hip/hip_runtime.h>

typedef float v2f __attribute__((ext_vector_type(2)));

#define NN 4096
#define TTOT 8192

constexpr int S    = 32;      // t per thread
constexpr int HALO = 4;       // dependency cone of 4 kernel-2 layers
constexpr int TN   = 64;      // n-rows per block
constexpr int TB   = 4 * S;   // 128 t-cols per block (4 waves)
constexpr int PITCH = TN + 4; // 68 floats, 16B-aligned rows

__device__ __forceinline__ float fexp2(float x) {
#if __has_builtin(__builtin_amdgcn_exp2f)
    return __builtin_amdgcn_exp2f(x);
#else
    return exp2f(x);
#endif
}
__device__ __forceinline__ float frcp(float x) {
#if __has_builtin(__builtin_amdgcn_rcpf)
    return __builtin_amdgcn_rcpf(x);
#else
    return 1.0f / x;
#endif
}
__device__ __forceinline__ v2f splat(float x) { v2f r = {x, x}; return r; }

__global__ __launch_bounds__(256) void gdcn_kernel(
    const float* __restrict__ x,
    const float* __restrict__ start_w,
    const float* __restrict__ start_b,
    const float* __restrict__ filter_w,
    const float* __restrict__ filter_b,
    const float* __restrict__ gate_w,
    const float* __restrict__ gate_b,
    float* __restrict__ out)
{
    __shared__ float tile[TN][PITCH];   // 64 x 68 x 4B = 17408 B

    const int tid = threadIdx.x;
    const int bn  = blockIdx.x & 63;          // 4096/64 = 64 n-blocks
    const int bt  = blockIdx.x >> 6;
    const int n0  = bn * TN;
    const int t0  = bt * TB;

    const int nl = tid & 63;                  // lane -> n row
    const int ts = tid >> 6;                  // wave -> t segment (wave-uniform edge)
    const int tbase = t0 + ts * S;

    const float* xr = x + (size_t)(n0 + nl) * TTOT + tbase;

    float v[S + HALO];
    const bool edge = (tbase + S + HALO > TTOT);   // only last segment of grid
    if (!edge) {
        #pragma unroll
        for (int q = 0; q < (S + HALO) / 4; ++q) {
            float4 f4 = *reinterpret_cast<const float4*>(xr + 4 * q);
            v[4*q+0] = f4.x; v[4*q+1] = f4.y; v[4*q+2] = f4.z; v[4*q+3] = f4.w;
        }
    } else {
        #pragma unroll
        for (int s = 0; s < S + HALO; ++s)
            v[s] = (tbase + s < TTOT) ? xr[s] : 0.0f;
    }

    constexpr float LOG2E = 1.4426950408889634f;

    // start 1x1 conv
    {
        const float sw = start_w[0], sb = start_b[0];
        #pragma unroll
        for (int s = 0; s < S + HALO; ++s) v[s] = fmaf(v[s], sw, sb);
        if (edge) {
            #pragma unroll
            for (int s = 0; s < S + HALO; ++s)
                if (tbase + s >= TTOT) v[s] = 0.0f;   // per-layer zero pad
        }
    }

    // 4 gated layers:
    // tanh(F)*sigmoid(G) = (ef-1) * rcp((ef+1)*(1+eg)),  ef=2^(2*log2e*F), eg=2^(-log2e*G)
    #pragma unroll
    for (int i = 0; i < 4; ++i) {
        const float ff0 = filter_w[2*i]   * (2.0f * LOG2E);
        const float ff1 = filter_w[2*i+1] * (2.0f * LOG2E);
        const float ffb = filter_b[i]     * (2.0f * LOG2E);
        const float gg0 = -gate_w[2*i]    * LOG2E;
        const float gg1 = -gate_w[2*i+1]  * LOG2E;
        const float ggb = -gate_b[i]      * LOG2E;
        const int len = S + HALO - 1 - i;     // 35,34,33,32

        #pragma unroll
        for (int s = 0; s + 1 < len; s += 2) {
            v2f a = { v[s],   v[s+1] };
            v2f b = { v[s+1], v[s+2] };
            v2f tf = a * splat(ff0) + b * splat(ff1) + splat(ffb);
            v2f tg = a * splat(gg0) + b * splat(gg1) + splat(ggb);
            if (i == 0) {   // layer-0 input unbounded: guard exp overflow (combined form)
                tf.x = fminf(tf.x, 126.0f); tf.y = fminf(tf.y, 126.0f);
                tg.x = fminf(tg.x, 126.0f); tg.y = fminf(tg.y, 126.0f);
            }
            v2f ef = { fexp2(tf.x), fexp2(tf.y) };
            v2f eg = { fexp2(tg.x), fexp2(tg.y) };
            v2f num = ef - splat(1.0f);
            v2f den = (ef + splat(1.0f)) * (eg + splat(1.0f));
            v2f r   = { frcp(den.x), frcp(den.y) };
            v2f res = num * r;
            v[s] = res.x; v[s+1] = res.y;
        }
        if (len & 1) {
            const int s = len - 1;
            float a = v[s], b = v[s + 1];
            float tf = fmaf(a, ff0, fmaf(b, ff1, ffb));
            float tg = fmaf(a, gg0, fmaf(b, gg1, ggb));
            if (i == 0) { tf = fminf(tf, 126.0f); tg = fminf(tg, 126.0f); }
            float ef = fexp2(tf), eg = fexp2(tg);
            v[s] = (ef - 1.0f) * frcp((ef + 1.0f) * (eg + 1.0f));
        }
        if (edge) {
            #pragma unroll
            for (int s = 0; s < len; ++s)
                if (tbase + s >= TTOT) v[s] = 0.0f;
        }
    }

    // transpose via LDS in two 16-col phases (keeps LDS at 17 KB)
    const int tl = tid >> 4;              // 0..15
    const int nq = (tid & 15) * 4;        // float4 column within n-tile
    #pragma unroll
    for (int p = 0; p < 2; ++p) {
        if (p) __syncthreads();           // protect phase-0 reads from phase-1 writes
        #pragma unroll
        for (int s = 0; s < 16; ++s)
            tile[ts * 16 + s][nl] = v[p * 16 + s];
        __syncthreads();
        #pragma unroll
        for (int k = 0; k < 4; ++k) {
            const int trow = tl + k * 16;   // tile row = wave k's element tl
            float4 w4 = *reinterpret_cast<const float4*>(&tile[trow][nq]);
            const int t = t0 + k * S + p * 16 + tl;
            *reinterpret_cast<float4*>(&out[(size_t)t * NN + n0 + nq]) = w4;
        }
    }
}

extern "C" void kernel_launch(void* const* d_in, const int* in_sizes, int n_in,
                              void* d_out, int out_size, void* d_ws, size_t ws_size,
                              hipStream_t stream) {
    const float* x  = (const float*)d_in[0];
    const float* sw = (const float*)d_in[1];
    const float* sb = (const float*)d_in[2];
    const float* fw = (const float*)d_in[3];
    const float* fb = (const float*)d_in[4];
    const float* gw = (const float*)d_in[5];
    const float* gb = (const float*)d_in[6];
    float* out = (float*)d_out;

    dim3 grid((NN / TN) * (TTOT / TB));   // 64 * 64 = 4096 blocks
    gdcn_kernel<<<grid, 256, 0, stream>>>(x, sw, sb, fw, fb, gw, gb, out);
}